// Round 3
// baseline (567.584 us; speedup 1.0000x reference)
//
#include <hip/hip_runtime.h>
#include <math.h>

#define HIDDEN   1024
#define IN_DIM   1152
#define OUT_D    512
#define EPS_C    1e-4f
#define BMA      64

typedef __attribute__((ext_vector_type(8))) __bf16 bf16x8;
typedef __attribute__((ext_vector_type(4))) float  f32x4;

#define MFMA16(a, b, c) __builtin_amdgcn_mfma_f32_16x16x32_bf16(a, b, c, 0, 0, 0)

static __device__ __forceinline__ unsigned short f2bf(float f) {
    union { float f; unsigned u; } v; v.f = f;
    unsigned r = v.u + 0x7fffu + ((v.u >> 16) & 1u);
    return (unsigned short)(r >> 16);
}

static __device__ __forceinline__ uint4 pack8(const float* v) {
    uint4 p;
    p.x = (unsigned)f2bf(v[0]) | ((unsigned)f2bf(v[1]) << 16);
    p.y = (unsigned)f2bf(v[2]) | ((unsigned)f2bf(v[3]) << 16);
    p.z = (unsigned)f2bf(v[4]) | ((unsigned)f2bf(v[5]) << 16);
    p.w = (unsigned)f2bf(v[6]) | ((unsigned)f2bf(v[7]) << 16);
    return p;
}

// tanh-form GELU via sigmoid: g = v * sigmoid(c1*v + c3*v^3), max err ~1e-3
static __device__ __forceinline__ float gelu_f(float v) {
    const float t = -v * (1.5957691216f + 0.0713548163f * v * v);
    return v / (1.0f + __expf(t));
}

// Pack W1 (rows permuted to k-major vec_local order) and W2 into bf16 MFMA B-fragments.
// Fragment (kt, nt): lane holds B[kt*32 + 8*(lane>>4) + i][nt*16 + (lane&15)], i=0..7,
// stored at frag*512 + lane*8 ushorts (one dwordx4 per lane).
// W1 row permutation: packed row kp in [128,512) reads orig row 128 + ((kp-128)&127)*3 + ((kp-128)>>7).
__global__ void pack_w_kernel(const float* __restrict__ W1, const float* __restrict__ W2,
                              unsigned short* __restrict__ w1p, unsigned short* __restrict__ w2p) {
    const int tid  = blockIdx.x * 256 + threadIdx.x;
    const int frag = tid >> 6;
    if (frag >= 2304 + 1024) return;
    const int lane = tid & 63;
    const float* W; unsigned short* outp; int Ndim, nt, kt, fl; bool perm;
    if (frag < 2304) { W = W1; outp = w1p; Ndim = 1024; fl = frag;        nt = fl & 63; kt = fl >> 6; perm = true;  }
    else             { W = W2; outp = w2p; Ndim = 512;  fl = frag - 2304; nt = fl & 31; kt = fl >> 5; perm = false; }
    const int k0 = kt * 32 + ((lane >> 4) << 3);
    const int n  = nt * 16 + (lane & 15);
    float v[8];
#pragma unroll
    for (int i = 0; i < 8; ++i) {
        int kp = k0 + i, ko = kp;
        if (perm && kp >= 128 && kp < 512) { const int q = kp - 128; ko = 128 + (q & 127) * 3 + (q >> 7); }
        v[i] = W[(size_t)ko * Ndim + n];
    }
    *reinterpret_cast<uint4*>(outp + (size_t)fl * 512 + lane * 8) = pack8(v);
}

// ===================== fused: features + GEMM1 + GELU + GEMM2 + rotation =====================
__global__ __launch_bounds__(1024, 4)
void fused_kernel(const float* __restrict__ x, const float* __restrict__ rot,
                  const float* __restrict__ extra, const float* __restrict__ b1,
                  const float* __restrict__ b2,
                  const bf16x8* __restrict__ w1p, const bf16x8* __restrict__ w2p,
                  float* __restrict__ out, int nrows) {
    // Phase A: x1 A-fragments (36 kt x 4 mt x 1KB = 147456 B)
    // Phase B: h  A-fragments (32 kt x 4 mt x 1KB = 131072 B)  [aliases]
    // Phase C: ys f32 [64][516] = 132096 B                      [aliases]
    __shared__ __align__(16) unsigned short buf[36 * 4 * 512];
    __shared__ float R_s[BMA * 9];

    const int tid  = threadIdx.x;
    const int row0 = blockIdx.x * BMA;

    // ---------------- phase 1: build x1 (bf16, k-major-permuted) in frag-major LDS ----------------
    {
        const int m   = tid >> 4;        // row 0..63
        const int l16 = tid & 15;
        const int i   = row0 + m;
        const int mt  = m >> 4;
        const int r8  = (m & 15) * 8;
        const bool valid = (i < nrows);
        const int f0 = l16 * 8;

        float r[9];
#pragma unroll
        for (int q = 0; q < 9; ++q) r[q] = 0.0f;
        float xv[4][8];
#pragma unroll
        for (int c = 0; c < 4; ++c)
#pragma unroll
            for (int q = 0; q < 8; ++q) xv[c][q] = 0.0f;

        if (valid) {
#pragma unroll
            for (int q = 0; q < 9; ++q) r[q] = rot[(size_t)i * 9 + q];
            const float* xp = x + (size_t)i * 512;
#pragma unroll
            for (int c = 0; c < 4; ++c) {
                float4 lo = *reinterpret_cast<const float4*>(xp + c * 128 + f0);
                float4 hi = *reinterpret_cast<const float4*>(xp + c * 128 + f0 + 4);
                xv[c][0]=lo.x; xv[c][1]=lo.y; xv[c][2]=lo.z; xv[c][3]=lo.w;
                xv[c][4]=hi.x; xv[c][5]=hi.y; xv[c][6]=hi.z; xv[c][7]=hi.w;
            }
        }
        if (l16 < 9) R_s[m * 9 + l16] = r[l16];

        // vectored 16B store of 8 bf16 at packed-k position k0 (k0 % 8 == 0)
        auto stw = [&](int k0v, const float* v8) {
            *reinterpret_cast<uint4*>(buf + ((k0v >> 5) * 4 + mt) * 512 + ((k0v >> 3) & 3) * 128 + r8) = pack8(v8);
        };

        stw(f0, xv[0]);                               // x[:,0]       -> k [0,128)
        float nv[8];
#pragma unroll
        for (int kk = 0; kk < 3; ++kk) {              // vec_local kk -> k [128+kk*128, +128) (k-major)
            float vl[8];
#pragma unroll
            for (int j = 0; j < 8; ++j)
                vl[j] = xv[1][j] * r[kk] + xv[2][j] * r[3 + kk] + xv[3][j] * r[6 + kk];
            stw(128 + kk * 128 + f0, vl);
        }
#pragma unroll
        for (int j = 0; j < 8; ++j)
            nv[j] = sqrtf(xv[1][j]*xv[1][j] + xv[2][j]*xv[2][j] + xv[3][j]*xv[3][j] + EPS_C);
        stw(512 + f0, nv);                            // vec_norm     -> k [512,640)

        const float* ep = extra + (size_t)i * 512 + l16 * 32;
#pragma unroll
        for (int q = 0; q < 4; ++q) {                 // extra        -> k [640,1152)
            float ev[8];
#pragma unroll
            for (int z = 0; z < 8; ++z) ev[z] = 0.0f;
            if (valid) {
                float4 lo = *reinterpret_cast<const float4*>(ep + q * 8);
                float4 hi = *reinterpret_cast<const float4*>(ep + q * 8 + 4);
                ev[0]=lo.x; ev[1]=lo.y; ev[2]=lo.z; ev[3]=lo.w;
                ev[4]=hi.x; ev[5]=hi.y; ev[6]=hi.z; ev[7]=hi.w;
            }
            stw(640 + l16 * 32 + q * 8, ev);
        }
    }
    __syncthreads();

    const int w    = tid >> 6;   // wave 0..15
    const int lane = tid & 63;
    const int lr   = lane & 15;
    const int lk   = lane >> 4;

    // ---------------- GEMM1: wave w owns N-cols [w*64, w*64+64) ----------------
    float bv1[4];
#pragma unroll
    for (int n = 0; n < 4; ++n) bv1[n] = b1[w * 64 + n * 16 + lr];

    f32x4 acc[4][4];
#pragma unroll
    for (int mt = 0; mt < 4; ++mt)
#pragma unroll
        for (int n = 0; n < 4; ++n) acc[mt][n] = (f32x4){0.f, 0.f, 0.f, 0.f};

    {
        const bf16x8* wb = w1p + (size_t)(w * 4) * 64 + lane;
        auto LB1 = [&](bf16x8* B, int kt) {
#pragma unroll
            for (int n = 0; n < 4; ++n) B[n] = wb[(size_t)kt * 4096 + n * 64];
        };
        auto MM1 = [&](const bf16x8* B, int kt) {
            const unsigned short* ab = buf + kt * 2048 + lane * 8;
#pragma unroll
            for (int mt = 0; mt < 4; ++mt) {
                const bf16x8 a = *reinterpret_cast<const bf16x8*>(ab + mt * 512);
#pragma unroll
                for (int n = 0; n < 4; ++n) acc[mt][n] = MFMA16(a, B[n], acc[mt][n]);
            }
        };
        bf16x8 B0[4], B1r[4];
        LB1(B0, 0);
        for (int kt = 0; kt < 34; kt += 2) {
            LB1(B1r, kt + 1);
            MM1(B0, kt);
            LB1(B0, kt + 2);
            MM1(B1r, kt + 1);
        }
        LB1(B1r, 35);
        MM1(B0, 34);
        MM1(B1r, 35);
    }
    __syncthreads();   // all x1 reads done; reuse buf as h fragments

    // ---------------- bias + GELU -> h frag-major ----------------
#pragma unroll
    for (int n = 0; n < 4; ++n) {
        const int ktn = w * 2 + (n >> 1);
        const int sub = ((n & 1) * 2 + (lr >> 3)) * 128 + (lr & 7);
#pragma unroll
        for (int mt = 0; mt < 4; ++mt)
#pragma unroll
            for (int j = 0; j < 4; ++j)
                buf[(ktn * 4 + mt) * 512 + sub + (lk * 4 + j) * 8] =
                    f2bf(gelu_f(acc[mt][n][j] + bv1[n]));
    }
    float bv2[2];
#pragma unroll
    for (int n = 0; n < 2; ++n) bv2[n] = b2[w * 32 + n * 16 + lr];
    __syncthreads();

    // ---------------- GEMM2: wave w owns N-cols [w*32, w*32+32) ----------------
    f32x4 acc2[4][2];
#pragma unroll
    for (int mt = 0; mt < 4; ++mt)
#pragma unroll
        for (int n = 0; n < 2; ++n) acc2[mt][n] = (f32x4){0.f, 0.f, 0.f, 0.f};

    {
        const bf16x8* wb2 = w2p + (size_t)(w * 2) * 64 + lane;
        auto LB2 = [&](bf16x8* C, int kt) {
#pragma unroll
            for (int n = 0; n < 2; ++n) C[n] = wb2[(size_t)kt * 2048 + n * 64];
        };
        auto MM2 = [&](const bf16x8* C, int kt) {
            const unsigned short* ab = buf + kt * 2048 + lane * 8;
#pragma unroll
            for (int mt = 0; mt < 4; ++mt) {
                const bf16x8 a = *reinterpret_cast<const bf16x8*>(ab + mt * 512);
#pragma unroll
                for (int n = 0; n < 2; ++n) acc2[mt][n] = MFMA16(a, C[n], acc2[mt][n]);
            }
        };
        bf16x8 C0[2], C1[2];
        LB2(C0, 0);
        for (int kt = 0; kt < 30; kt += 2) {
            LB2(C1, kt + 1);
            MM2(C0, kt);
            LB2(C0, kt + 2);
            MM2(C1, kt + 1);
        }
        LB2(C1, 31);
        MM2(C0, 30);
        MM2(C1, 31);
    }
    __syncthreads();   // all h reads done; reuse buf as ys f32 [64][516]

    float* ys = reinterpret_cast<float*>(buf);
#pragma unroll
    for (int n = 0; n < 2; ++n) {
        const int col = w * 32 + n * 16 + lr;
#pragma unroll
        for (int mt = 0; mt < 4; ++mt)
#pragma unroll
            for (int j = 0; j < 4; ++j)
                ys[(mt * 16 + lk * 4 + j) * 516 + col] = acc2[mt][n][j] + bv2[n];
    }
    __syncthreads();

    // ---------------- epilogue: rotation + coalesced store ----------------
    {
        const int c    = tid & 511;      // output column
        const int half = tid >> 9;       // row half
        const int p    = c >> 7;
        const int f    = c & 127;
        const int m0   = half * 32;
        float* op = out + (size_t)(row0 + m0) * 512 + c;
        if (p == 0) {
#pragma unroll 4
            for (int mm = 0; mm < 32; ++mm)
                if (row0 + m0 + mm < nrows) op[(size_t)mm * 512] = ys[(m0 + mm) * 516 + f];
        } else {
            const int cc = p - 1;
#pragma unroll 4
            for (int mm = 0; mm < 32; ++mm) {
                const int m = m0 + mm;
                if (row0 + m < nrows) {
                    op[(size_t)mm * 512] =
                          R_s[m * 9 + cc * 3 + 0] * ys[m * 516 + 128 + f]
                        + R_s[m * 9 + cc * 3 + 1] * ys[m * 516 + 256 + f]
                        + R_s[m * 9 + cc * 3 + 2] * ys[m * 516 + 384 + f];
                }
            }
        }
    }
}

extern "C" void kernel_launch(void* const* d_in, const int* in_sizes, int n_in,
                              void* d_out, int out_size, void* d_ws, size_t ws_size,
                              hipStream_t stream) {
    const float* x     = (const float*)d_in[0];
    const float* rot   = (const float*)d_in[1];
    const float* extra = (const float*)d_in[2];
    const float* W1    = (const float*)d_in[3];
    const float* b1    = (const float*)d_in[4];
    const float* W2    = (const float*)d_in[5];
    const float* b2    = (const float*)d_in[6];
    float* out = (float*)d_out;

    const int nrows = in_sizes[0] / 512;

    // ws: W1 packed (2304 frags * 1024 B) | W2 packed (1024 frags * 1024 B)
    unsigned short* w1p = (unsigned short*)d_ws;
    unsigned short* w2p = (unsigned short*)((char*)d_ws + (size_t)2304 * 1024);

    pack_w_kernel<<<(3328 * 64 + 255) / 256, 256, 0, stream>>>(W1, W2, w1p, w2p);

    const int nblk = (nrows + BMA - 1) / BMA;
    fused_kernel<<<nblk, 1024, 0, stream>>>(x, rot, extra, b1, b2,
                                            (const bf16x8*)w1p, (const bf16x8*)w2p,
                                            out, nrows);
}

// Round 4
// 495.496 us; speedup vs baseline: 1.1455x; 1.1455x over previous
//
#include <hip/hip_runtime.h>
#include <math.h>

#define HIDDEN   1024
#define IN_DIM   1152
#define OUT_D    512
#define EPS_C    1e-4f
#define BMA      64

typedef __attribute__((ext_vector_type(8))) __bf16 bf16x8;
typedef __attribute__((ext_vector_type(4))) float  f32x4;

#define MFMA16(a, b, c) __builtin_amdgcn_mfma_f32_16x16x32_bf16(a, b, c, 0, 0, 0)

static __device__ __forceinline__ unsigned short f2bf(float f) {
    union { float f; unsigned u; } v; v.f = f;
    unsigned r = v.u + 0x7fffu + ((v.u >> 16) & 1u);
    return (unsigned short)(r >> 16);
}

static __device__ __forceinline__ uint4 pack8(const float* v) {
    uint4 p;
    p.x = (unsigned)f2bf(v[0]) | ((unsigned)f2bf(v[1]) << 16);
    p.y = (unsigned)f2bf(v[2]) | ((unsigned)f2bf(v[3]) << 16);
    p.z = (unsigned)f2bf(v[4]) | ((unsigned)f2bf(v[5]) << 16);
    p.w = (unsigned)f2bf(v[6]) | ((unsigned)f2bf(v[7]) << 16);
    return p;
}

// tanh-form GELU via sigmoid: g = v * sigmoid(c1*v + c3*v^3), max err ~1e-3
static __device__ __forceinline__ float gelu_f(float v) {
    const float t = -v * (1.5957691216f + 0.0713548163f * v * v);
    return v / (1.0f + __expf(t));
}

// Pack W1 (rows permuted to k-major vec_local order) and W2 into bf16 MFMA B-fragments.
// Fragment (kt, nt): lane holds B[kt*32 + 8*(lane>>4) + i][nt*16 + (lane&15)], i=0..7,
// stored at frag*512 + lane*8 ushorts.
// W1 row permutation: packed row kp in [128,512) reads orig row 128 + ((kp-128)&127)*3 + ((kp-128)>>7).
__global__ void pack_w_kernel(const float* __restrict__ W1, const float* __restrict__ W2,
                              unsigned short* __restrict__ w1p, unsigned short* __restrict__ w2p) {
    const int tid  = blockIdx.x * 256 + threadIdx.x;
    const int frag = tid >> 6;
    if (frag >= 2304 + 1024) return;
    const int lane = tid & 63;
    const float* W; unsigned short* outp; int Ndim, nt, kt, fl; bool perm;
    if (frag < 2304) { W = W1; outp = w1p; Ndim = 1024; fl = frag;        nt = fl & 63; kt = fl >> 6; perm = true;  }
    else             { W = W2; outp = w2p; Ndim = 512;  fl = frag - 2304; nt = fl & 31; kt = fl >> 5; perm = false; }
    const int k0 = kt * 32 + ((lane >> 4) << 3);
    const int n  = nt * 16 + (lane & 15);
    float v[8];
#pragma unroll
    for (int i = 0; i < 8; ++i) {
        int kp = k0 + i, ko = kp;
        if (perm && kp >= 128 && kp < 512) { const int q = kp - 128; ko = 128 + (q & 127) * 3 + (q >> 7); }
        v[i] = W[(size_t)ko * Ndim + n];
    }
    *reinterpret_cast<uint4*>(outp + (size_t)fl * 512 + lane * 8) = pack8(v);
}

// ===================== fused: features + GEMM1 + GELU + GEMM2 + rotation =====================
__global__ __launch_bounds__(1024, 4)
void fused_kernel(const float* __restrict__ x, const float* __restrict__ rot,
                  const float* __restrict__ extra, const float* __restrict__ b1,
                  const float* __restrict__ b2,
                  const bf16x8* __restrict__ w1p, const bf16x8* __restrict__ w2p,
                  float* __restrict__ out, int nrows) {
    // x1 A-frag image: 36 kt x 4 mt x 1KB = 147456 B; h frags (131072 B) alias chunks 0..7
    __shared__ __align__(16) unsigned short buf[36 * 4 * 512];
    __shared__ float R_s[BMA * 9];

    const int tid  = threadIdx.x;
    const int row0 = blockIdx.x * BMA;
    const int w    = tid >> 6;   // wave 0..15
    const int lane = tid & 63;
    const int lr   = lane & 15;
    const int lk   = lane >> 4;

    // ---- staging role: wave w stages frag (kt_local = w>>2, mt = w&3) of a chunk ----
    const int skt = w >> 2;
    const int smt = w & 3;
    int srow = row0 + smt * 16 + lr;
    if (srow > nrows - 1) srow = nrows - 1;
    const int soff = skt * 32 + lk * 8;                  // col offset within chunk
    const float* sxp = x + (size_t)srow * 512 + soff;    // x0 chunk source (cols 0..127)
    const float* sep = extra + (size_t)srow * 512 + soff;// extra chunks: + (cc-5)*128

    // issue x0 loads early (consumed after phase-1-lite)
    const float4 xl0 = *reinterpret_cast<const float4*>(sxp);
    const float4 xl1 = *reinterpret_cast<const float4*>(sxp + 4);

    // ---------------- phase-1-lite: vec_local (k-major) + vec_norm -> k [128,640) ----------------
    {
        const int m   = tid >> 4;
        const int l16 = tid & 15;
        const int mt  = m >> 4;
        const int r8u = (m & 15) * 8;
        int i = row0 + m; if (i > nrows - 1) i = nrows - 1;
        float r[9];
#pragma unroll
        for (int q = 0; q < 9; ++q) r[q] = rot[(size_t)i * 9 + q];
        if (l16 < 9) R_s[m * 9 + l16] = r[l16];
        const float* xp = x + (size_t)i * 512 + l16 * 8;
        float xv[3][8];
#pragma unroll
        for (int c = 0; c < 3; ++c) {
            float4 lo = *reinterpret_cast<const float4*>(xp + (c + 1) * 128);
            float4 hi = *reinterpret_cast<const float4*>(xp + (c + 1) * 128 + 4);
            xv[c][0]=lo.x; xv[c][1]=lo.y; xv[c][2]=lo.z; xv[c][3]=lo.w;
            xv[c][4]=hi.x; xv[c][5]=hi.y; xv[c][6]=hi.z; xv[c][7]=hi.w;
        }
        auto stw = [&](int k0v, const float* v8) {
            *reinterpret_cast<uint4*>(buf + ((k0v >> 5) * 4 + mt) * 512 + ((k0v >> 3) & 3) * 128 + r8u) = pack8(v8);
        };
#pragma unroll
        for (int kk = 0; kk < 3; ++kk) {
            float vl[8];
#pragma unroll
            for (int j = 0; j < 8; ++j)
                vl[j] = xv[0][j] * r[kk] + xv[1][j] * r[3 + kk] + xv[2][j] * r[6 + kk];
            stw(128 + kk * 128 + l16 * 8, vl);
        }
        float nv[8];
#pragma unroll
        for (int j = 0; j < 8; ++j)
            nv[j] = sqrtf(xv[0][j]*xv[0][j] + xv[1][j]*xv[1][j] + xv[2][j]*xv[2][j] + EPS_C);
        stw(512 + l16 * 8, nv);
    }
    // x0 chunk: pack + ds_write (frag index == w, so addr = tid*16 B)
    {
        float v8[8];
        v8[0]=xl0.x; v8[1]=xl0.y; v8[2]=xl0.z; v8[3]=xl0.w;
        v8[4]=xl1.x; v8[5]=xl1.y; v8[6]=xl1.z; v8[7]=xl1.w;
        *reinterpret_cast<uint4*>(buf + tid * 8) = pack8(v8);
    }
    __syncthreads();

    // ---------------- GEMM1: 9 chunks of 4 kt; extra chunks (5..8) reg-staged in-loop ----------------
    float bv1[4];
#pragma unroll
    for (int n = 0; n < 4; ++n) bv1[n] = b1[w * 64 + n * 16 + lr];

    f32x4 acc[4][4];
#pragma unroll
    for (int mt = 0; mt < 4; ++mt)
#pragma unroll
        for (int n = 0; n < 4; ++n) acc[mt][n] = (f32x4){0.f, 0.f, 0.f, 0.f};

    const bf16x8* wb = w1p + (size_t)(w * 4) * 64 + lane;
    auto LB1 = [&](bf16x8* B, int kt) {
#pragma unroll
        for (int n = 0; n < 4; ++n) B[n] = wb[(size_t)kt * 4096 + n * 64];
    };
    auto MM1 = [&](const bf16x8* B, int kt) {
        const unsigned short* ab = buf + kt * 2048 + lane * 8;
#pragma unroll
        for (int mt = 0; mt < 4; ++mt) {
            const bf16x8 a = *reinterpret_cast<const bf16x8*>(ab + mt * 512);
#pragma unroll
            for (int n = 0; n < 4; ++n) acc[mt][n] = MFMA16(a, B[n], acc[mt][n]);
        }
    };

    bf16x8 Bb[2][4];
    LB1(Bb[0], 0);
#pragma unroll
    for (int c = 0; c < 9; ++c) {
        float4 el0, el1;
        if (c >= 3 && c <= 6) {   // issue loads for extra chunk cc = c+2 (HBM latency hides under 4 kt)
            el0 = *reinterpret_cast<const float4*>(sep + (c - 3) * 128);
            el1 = *reinterpret_cast<const float4*>(sep + (c - 3) * 128 + 4);
        }
#pragma unroll
        for (int p = 0; p < 4; ++p) {
            const int kt = 4 * c + p;
            if (kt < 35) LB1(Bb[(kt + 1) & 1], kt + 1);
            MM1(Bb[kt & 1], kt);
        }
        if (c >= 3 && c <= 6) {   // pack + ds_write chunk c+2
            float v8[8];
            v8[0]=el0.x; v8[1]=el0.y; v8[2]=el0.z; v8[3]=el0.w;
            v8[4]=el1.x; v8[5]=el1.y; v8[6]=el1.z; v8[7]=el1.w;
            const int ktg = 4 * (c + 2) + skt;
            *reinterpret_cast<uint4*>(buf + (ktg * 4 + smt) * 512 + lane * 8) = pack8(v8);
        }
        if (c >= 4 && c < 8) __syncthreads();
    }
    // After the c=7 barrier all waves only read chunk 8 (bytes >=131072); h frags use [0,131072): no barrier needed.

    // ---------------- bias + GELU -> h frag-major ----------------
#pragma unroll
    for (int n = 0; n < 4; ++n) {
        const int ktn = w * 2 + (n >> 1);
        const int sub = ((n & 1) * 2 + (lr >> 3)) * 128 + (lr & 7);
#pragma unroll
        for (int mt = 0; mt < 4; ++mt)
#pragma unroll
            for (int j = 0; j < 4; ++j)
                buf[(ktn * 4 + mt) * 512 + sub + (lk * 4 + j) * 8] =
                    f2bf(gelu_f(acc[mt][n][j] + bv1[n]));
    }
    __syncthreads();

    // ---------------- GEMM2: wave (mh = w>>3) x (g = w&7); nt = {g, g+8, g+16, g+24} ----------------
    const int mh = w >> 3;
    const int g  = w & 7;
    float bv2[4];
#pragma unroll
    for (int p = 0; p < 4; ++p) bv2[p] = b2[p * 128 + g * 16 + lr];

    f32x4 acc2[2][4];
#pragma unroll
    for (int mtl = 0; mtl < 2; ++mtl)
#pragma unroll
        for (int p = 0; p < 4; ++p) acc2[mtl][p] = (f32x4){0.f, 0.f, 0.f, 0.f};

    const bf16x8* wb2 = w2p + (size_t)g * 64 + lane;
    auto LB2 = [&](bf16x8* C, int kt2) {
#pragma unroll
        for (int p = 0; p < 4; ++p) C[p] = wb2[(size_t)kt2 * 2048 + p * 512];
    };
    auto MM2 = [&](const bf16x8* C, int kt2) {
        const unsigned short* ab = buf + kt2 * 2048 + lane * 8 + (mh * 2) * 512;
#pragma unroll
        for (int mtl = 0; mtl < 2; ++mtl) {
            const bf16x8 a = *reinterpret_cast<const bf16x8*>(ab + mtl * 512);
#pragma unroll
            for (int p = 0; p < 4; ++p) acc2[mtl][p] = MFMA16(a, C[p], acc2[mtl][p]);
        }
    };

    bf16x8 Cb[4][4];   // 4-deep ring (covers ~3 kt2 of L2 latency)
    LB2(Cb[0], 0); LB2(Cb[1], 1); LB2(Cb[2], 2);
#pragma unroll
    for (int kt2 = 0; kt2 < 32; ++kt2) {
        if (kt2 + 3 < 32) LB2(Cb[(kt2 + 3) & 3], kt2 + 3);
        MM2(Cb[kt2 & 3], kt2);
    }

    // ---------------- epilogue: in-register rotation + store ----------------
    {
        const int fcol = g * 16 + lr;
#pragma unroll
        for (int mtl = 0; mtl < 2; ++mtl) {
#pragma unroll
            for (int j = 0; j < 4; ++j) {
                const int rl = (mh * 2 + mtl) * 16 + lk * 4 + j;
                if (row0 + rl < nrows) {
                    const float* Rp = R_s + rl * 9;
                    const float y0 = acc2[mtl][0][j] + bv2[0];
                    const float y1 = acc2[mtl][1][j] + bv2[1];
                    const float y2 = acc2[mtl][2][j] + bv2[2];
                    const float y3 = acc2[mtl][3][j] + bv2[3];
                    float* op = out + (size_t)(row0 + rl) * 512 + fcol;
                    op[0]   = y0;
                    op[128] = Rp[0] * y1 + Rp[1] * y2 + Rp[2] * y3;
                    op[256] = Rp[3] * y1 + Rp[4] * y2 + Rp[5] * y3;
                    op[384] = Rp[6] * y1 + Rp[7] * y2 + Rp[8] * y3;
                }
            }
        }
    }
}

extern "C" void kernel_launch(void* const* d_in, const int* in_sizes, int n_in,
                              void* d_out, int out_size, void* d_ws, size_t ws_size,
                              hipStream_t stream) {
    const float* x     = (const float*)d_in[0];
    const float* rot   = (const float*)d_in[1];
    const float* extra = (const float*)d_in[2];
    const float* W1    = (const float*)d_in[3];
    const float* b1    = (const float*)d_in[4];
    const float* W2    = (const float*)d_in[5];
    const float* b2    = (const float*)d_in[6];
    float* out = (float*)d_out;

    const int nrows = in_sizes[0] / 512;

    // ws: W1 packed (2304 frags * 1024 B) | W2 packed (1024 frags * 1024 B)
    unsigned short* w1p = (unsigned short*)d_ws;
    unsigned short* w2p = (unsigned short*)((char*)d_ws + (size_t)2304 * 1024);

    pack_w_kernel<<<(3328 * 64 + 255) / 256, 256, 0, stream>>>(W1, W2, w1p, w2p);

    const int nblk = (nrows + BMA - 1) / BMA;
    fused_kernel<<<nblk, 1024, 0, stream>>>(x, rot, extra, b1, b2,
                                            (const bf16x8*)w1p, (const bf16x8*)w2p,
                                            out, nrows);
}